// Round 5
// baseline (4014.053 us; speedup 1.0000x reference)
//
#include <hip/hip_runtime.h>
#include <hip/hip_bf16.h>

typedef __hip_bfloat16 bf16;

#define HH 256
#define WW 256
#define HW 65536
#define NB 8

__device__ __forceinline__ float b2f(bf16 v){ return __bfloat162float(v); }
__device__ __forceinline__ bf16 f2b(float v){ return __float2bfloat16(v); }

__device__ __forceinline__ float loadAs(const void* p, long i, int isF32){
    return isF32 ? ((const float*)p)[i] : b2f(((const bf16*)p)[i]);
}
__device__ __forceinline__ void storeAs(void* p, long i, float v, int isF32){
    if (isF32) ((float*)p)[i] = v; else ((bf16*)p)[i] = f2b(v);
}

// Detect storage dtype: bf16 (flag=0) vs f32 (flag=1).
// f32 N(0,1) read as u16: low words are mantissa bits -> wild "exponent" fields.
__global__ void detect_kernel(const unsigned short* __restrict__ p, int n, int* flag)
{
    int t = threadIdx.x;
    int crazy = 0;
    for (int i = t; i < n; i += 64) {
        int e = (p[i] >> 7) & 0xFF;
        if (e != 0 && (e < 100 || e > 150)) crazy++;
    }
    for (int o = 32; o; o >>= 1) crazy += __shfl_down(crazy, o);
    if (t == 0) *flag = (crazy > n / 8) ? 1 : 0;
}

struct Ptr14 { const void* p[14]; };

__global__ void conv_weights_kernel(Ptr14 ptrs, const int* __restrict__ flag,
                                    float* __restrict__ dst)
{
    const int sz[14] = {144,16,9216,64,81, 144,16,9216,64,81, 1152,64,576,1};
    int isF32 = *flag;
    int idx = blockIdx.x * 256 + threadIdx.x;
    if (idx >= 20835) return;
    int a = 0, base = 0;
    while (a < 13 && idx >= base + sz[a]) { base += sz[a]; a++; }
    dst[idx] = loadAs(ptrs.p[a], idx - base, isF32);
}

// repack w3 [81][64][3][3] -> wp[ct*81 + k] (f32), ct = c*9 + tap
__global__ void repack_w3_kernel(const void* __restrict__ w, float* __restrict__ wp,
                                 const int* __restrict__ flag)
{
    int isF32 = *flag;
    int p = blockIdx.x * 256 + threadIdx.x;
    if (p >= 81 * 576) return;
    int k  = p % 81;
    int ct = p / 81;
    wp[p] = loadAs(w, (long)k * 576 + ct, isF32);
}

// d (region 2 of d_out, element offset 2*NB*HW) = origin - residual
__global__ void d_kernel(const void* __restrict__ origin, const void* __restrict__ residual,
                         const int* __restrict__ flag, void* __restrict__ outBase)
{
    int isF32 = *flag;
    int i = blockIdx.x * 256 + threadIdx.x;
    if (i >= NB * HW) return;
    storeAs(outBase, (long)2 * NB * HW + i,
            loadAs(origin, i, isF32) - loadAs(residual, i, isF32), isF32);
}

// conv 1->16 rows [a1, a1+rows1), ReLU -> h1 band [ig][row-(r0-2)][ch16][x]
// src element base = (srcImg0 + ig) * HW
__global__ void conv1_band(const void* __restrict__ src, const int* __restrict__ flag,
                           const float* __restrict__ w, const float* __restrict__ bias,
                           bf16* __restrict__ h1g, int srcImg0, int r0, int bandH, int a1, int rows1)
{
    int isF32 = *flag;
    int ig = blockIdx.y;
    int bx = blockIdx.x; int ch = bx / rows1; int ry = bx - ch * rows1;
    int y = a1 + ry; int x = threadIdx.x;
    const long sb = (long)(srcImg0 + ig) * HW;
    float acc = bias[ch];
    const float* wp = w + ch * 9;
    #pragma unroll
    for (int dy = 0; dy < 3; dy++) {
        int yy = y + dy - 1;
        if ((unsigned)yy >= HH) continue;
        #pragma unroll
        for (int dx = 0; dx < 3; dx++) {
            int xx = x + dx - 1;
            if ((unsigned)xx >= WW) continue;
            acc = fmaf(wp[dy * 3 + dx], loadAs(src, sb + (yy << 8) + xx, isF32), acc);
        }
    }
    h1g[((long)ig * (bandH + 4) + (y - (r0 - 2))) * 4096 + ch * 256 + x] = f2b(fmaxf(acc, 0.f));
}

// conv 16->64 rows [a2, a2+rows2) from h1 band, ReLU -> h2 band [ig][row-(r0-1)][ch64][x]
__global__ void conv2_band(const bf16* __restrict__ h1g, const float* __restrict__ w,
                           const float* __restrict__ bias, bf16* __restrict__ h2g,
                           int r0, int bandH, int a2, int rows2)
{
    int ig = blockIdx.y;
    int bx = blockIdx.x; int co = bx / rows2; int ry = bx - co * rows2;
    int y = a2 + ry; int x = threadIdx.x;
    const bf16* h1 = h1g + (long)ig * (bandH + 4) * 4096;
    float acc = bias[co];
    const float* wp = w + co * 144;
    for (int c = 0; c < 16; c++) {
        #pragma unroll
        for (int dy = 0; dy < 3; dy++) {
            int yy = y + dy - 1;
            if ((unsigned)yy >= HH) continue;
            long rb = (long)(yy - (r0 - 2)) * 4096 + c * 256;
            #pragma unroll
            for (int dx = 0; dx < 3; dx++) {
                int xx = x + dx - 1;
                if ((unsigned)xx >= WW) continue;
                acc = fmaf(wp[c * 9 + dy * 3 + dx], b2f(h1[rb + xx]), acc);
            }
        }
    }
    h2g[((long)ig * (bandH + 2) + (y - (r0 - 1))) * 16384 + co * 256 + x] = f2b(fmaxf(acc, 0.f));
}

// fused conv 64->81 + softmax + 9x9 dynamic filter; rows [r0, r0+bandH)
// src images at (srcImg0+ig)*HW, dst at (dstImg0+ig)*HW — both inside outBase/src bases
__global__ void __launch_bounds__(256)
filter_band(const bf16* __restrict__ h2g, const float* __restrict__ w3, const float* __restrict__ b3,
            const void* __restrict__ src, const int* __restrict__ flag,
            void* __restrict__ dst, int srcImg0, int dstImg0, int r0, int bandH)
{
    int isF32 = *flag;
    int ig = blockIdx.y;
    int y = r0 + blockIdx.x; int x = threadIdx.x;
    const bf16* h2 = h2g + (long)ig * (bandH + 2) * 16384;

    float logit[81];
    #pragma unroll
    for (int k = 0; k < 81; k++) logit[k] = b3[k];

    for (int c = 0; c < 64; c++) {
        #pragma unroll
        for (int dy = 0; dy < 3; dy++) {
            int yy = y + dy - 1;
            if ((unsigned)yy >= HH) continue;
            long rb = (long)(yy - (r0 - 1)) * 16384 + c * 256;
            #pragma unroll
            for (int dx = 0; dx < 3; dx++) {
                int xx = x + dx - 1;
                if ((unsigned)xx >= WW) continue;
                float v = b2f(h2[rb + xx]);
                const float* wk = w3 + (c * 9 + dy * 3 + dx) * 81;
                #pragma unroll
                for (int k = 0; k < 81; k++) logit[k] = fmaf(v, wk[k], logit[k]);
            }
        }
    }
    float m = logit[0];
    #pragma unroll
    for (int k = 1; k < 81; k++) m = fmaxf(m, logit[k]);
    float ssum = 0.f;
    #pragma unroll
    for (int k = 0; k < 81; k++) { float e = __expf(logit[k] - m); logit[k] = e; ssum += e; }
    float inv = 1.f / ssum;
    const long sb = (long)(srcImg0 + ig) * HW;
    float acc = 0.f;
    #pragma unroll
    for (int i = 0; i < 9; i++) {
        int yy = y + i - 4;
        if ((unsigned)yy >= HH) continue;
        #pragma unroll
        for (int j = 0; j < 9; j++) {
            int xx = x + j - 4;
            if ((unsigned)xx >= WW) continue;
            acc = fmaf(logit[i * 9 + j], loadAs(src, sb + (yy << 8) + xx, isF32), acc);
        }
    }
    storeAs(dst, (long)(dstImg0 + ig) * HW + (y << 8) + x, acc * inv, isF32);
}

// c1: conv 2->64 on (x_ at xImg0, g_ at gImg0 inside outBase), ReLU -> hb band
__global__ void c1_band(const void* __restrict__ outBase, const int* __restrict__ flag,
                        const float* __restrict__ w, const float* __restrict__ bias,
                        bf16* __restrict__ hb, int xImg0, int gImg0,
                        int r0, int bandH, int ac, int rowsc)
{
    int isF32 = *flag;
    int ig = blockIdx.y;
    int bx = blockIdx.x; int co = bx / rowsc; int ry = bx - co * rowsc;
    int y = ac + ry; int x = threadIdx.x;
    const long sbx = (long)(xImg0 + ig) * HW;
    const long sbg = (long)(gImg0 + ig) * HW;
    float acc = bias[co];
    const float* wp = w + co * 18;
    #pragma unroll
    for (int dy = 0; dy < 3; dy++) {
        int yy = y + dy - 1;
        if ((unsigned)yy >= HH) continue;
        #pragma unroll
        for (int dx = 0; dx < 3; dx++) {
            int xx = x + dx - 1;
            if ((unsigned)xx >= WW) continue;
            long o = (yy << 8) + xx;
            acc = fmaf(wp[dy * 3 + dx],     loadAs(outBase, sbx + o, isF32), acc);
            acc = fmaf(wp[9 + dy * 3 + dx], loadAs(outBase, sbg + o, isF32), acc);
        }
    }
    hb[((long)ig * (bandH + 2) + (y - (r0 - 1))) * 16384 + co * 256 + x] = f2b(fmaxf(acc, 0.f));
}

// s = conv 64->1 of hb; out1 = s (region 1); out0 = s + d (region 0); d in region 2
__global__ void final_band(const bf16* __restrict__ hb, const float* __restrict__ w,
                           const float* __restrict__ bias, const int* __restrict__ flag,
                           void* __restrict__ outBase, int img0, int r0, int bandH)
{
    int isF32 = *flag;
    int ig = blockIdx.y;
    int y = r0 + blockIdx.x; int x = threadIdx.x;
    const bf16* h = hb + (long)ig * (bandH + 2) * 16384;
    float acc = bias[0];
    for (int c = 0; c < 64; c++) {
        #pragma unroll
        for (int dy = 0; dy < 3; dy++) {
            int yy = y + dy - 1;
            if ((unsigned)yy >= HH) continue;
            long rb = (long)(yy - (r0 - 1)) * 16384 + c * 256;
            #pragma unroll
            for (int dx = 0; dx < 3; dx++) {
                int xx = x + dx - 1;
                if ((unsigned)xx >= WW) continue;
                acc = fmaf(w[c * 9 + dy * 3 + dx], b2f(h[rb + xx]), acc);
            }
        }
    }
    long pix = (long)(img0 + ig) * HW + (y << 8) + x;
    float d = loadAs(outBase, (long)2 * NB * HW + pix, isF32);
    storeAs(outBase, (long)NB * HW + pix, acc, isF32);          // s  -> region 1
    storeAs(outBase, pix, acc + d, isF32);                      // out -> region 0
}

extern "C" void kernel_launch(void* const* d_in, const int* in_sizes, int n_in,
                              void* d_out, int out_size, void* d_ws, size_t ws_size,
                              hipStream_t stream)
{
    const void* origin   = d_in[0];
    const void* residual = d_in[1];

    int* flag = (int*)d_ws;
    float* ws = (float*)d_ws;
    long off = 16;
    float* wf  = ws + off; off += 20835;
    float* w3x = ws + off; off += 46656;
    float* w3g = ws + off; off += 46656;
    long fixedF = off;                       // ~457KB
    size_t actB = ws_size > (size_t)fixedF * 4 ? ws_size - (size_t)fixedF * 4 : 0;

    int GI = 1, BH = 4; long best = -1;
    const int gis[4] = {1,2,4,8}; const int bhs[7] = {4,8,16,32,64,128,256};
    for (int a = 0; a < 4; a++) for (int b = 0; b < 7; b++) {
        long gi = gis[a], bh = bhs[b];
        long branchB = gi * ((bh + 4) * 4096L * 2 + (bh + 2) * 16384L * 2);
        long tailB   = 2L * gi * (bh + 2) * 16384L * 2;
        long need = branchB > tailB ? branchB : tailB;
        long score = gi * bh * 16 + gi;
        if ((size_t)need <= actB && score > best) { best = score; GI = (int)gi; BH = (int)bh; }
    }
    bf16* actBase = (bf16*)(ws + fixedF);
    bf16* h1g = actBase;
    bf16* h2g = h1g + (long)GI * (BH + 4) * 4096;
    bf16* hb0 = actBase;
    bf16* hb1 = hb0 + (long)GI * (BH + 2) * 16384;

    const int fx_w1o=0, fx_b1o=144, fx_w2o=160, fx_b2o=9376, fx_b3o=9440;
    const int fg_w1o=9521, fg_b1o=9665, fg_w2o=9681, fg_b2o=18897, fg_b3o=18961;
    const int c1_wo=19042, c1_bo=20194, c2_wo=20258, c2_bo=20834;

    detect_kernel<<<1, 64, 0, stream>>>((const unsigned short*)origin, 4096, flag);
    Ptr14 wp;
    wp.p[0]=d_in[2];  wp.p[1]=d_in[3];  wp.p[2]=d_in[4];  wp.p[3]=d_in[5];  wp.p[4]=d_in[7];
    wp.p[5]=d_in[8];  wp.p[6]=d_in[9];  wp.p[7]=d_in[10]; wp.p[8]=d_in[11]; wp.p[9]=d_in[13];
    wp.p[10]=d_in[14]; wp.p[11]=d_in[15]; wp.p[12]=d_in[16]; wp.p[13]=d_in[17];
    conv_weights_kernel<<<(20835 + 255) / 256, 256, 0, stream>>>(wp, flag, wf);
    repack_w3_kernel<<<(46656 + 255) / 256, 256, 0, stream>>>(d_in[6],  w3x, flag);
    repack_w3_kernel<<<(46656 + 255) / 256, 256, 0, stream>>>(d_in[12], w3g, flag);
    d_kernel<<<(NB * HW) / 256, 256, 0, stream>>>(origin, residual, flag, d_out);

    int nBands = 256 / BH;
    for (int g0 = 0; g0 < NB; g0 += GI) {
        // ---- branch phase: both dyn-filter branches, band by band ----
        for (int bd = 0; bd < nBands; bd++) {
            int r0 = bd * BH;
            int a1 = r0 - 2 > 0 ? r0 - 2 : 0;
            int b1 = r0 + BH + 2 < 256 ? r0 + BH + 2 : 256;
            int rows1 = b1 - a1;
            int a2 = r0 - 1 > 0 ? r0 - 1 : 0;
            int b2 = r0 + BH + 1 < 256 ? r0 + BH + 1 : 256;
            int rows2 = b2 - a2;
            dim3 gc1(16 * rows1, GI), gc2(64 * rows2, GI), gfl(BH, GI);
            // x branch: src = residual (input), x_ -> region 0 images g0..
            conv1_band<<<gc1, 256, 0, stream>>>(residual, flag, wf + fx_w1o, wf + fx_b1o,
                                                h1g, g0, r0, BH, a1, rows1);
            conv2_band<<<gc2, 256, 0, stream>>>(h1g, wf + fx_w2o, wf + fx_b2o, h2g, r0, BH, a2, rows2);
            filter_band<<<gfl, 256, 0, stream>>>(h2g, w3x, wf + fx_b3o, residual, flag,
                                                 d_out, g0, g0, r0, BH);
            // g branch: src = d (region 2 of d_out => img offset 2*NB), g_ -> region 1
            conv1_band<<<gc1, 256, 0, stream>>>(d_out, flag, wf + fg_w1o, wf + fg_b1o,
                                                h1g, g0 + 2 * NB, r0, BH, a1, rows1);
            conv2_band<<<gc2, 256, 0, stream>>>(h1g, wf + fg_w2o, wf + fg_b2o, h2g, r0, BH, a2, rows2);
            filter_band<<<gfl, 256, 0, stream>>>(h2g, w3g, wf + fg_b3o, d_out, flag,
                                                 d_out, g0 + 2 * NB, g0 + NB, r0, BH);
        }
        // ---- tail phase: staggered so final(bd-1) launches after c1(bd) ----
        for (int bd = 0; bd < nBands; bd++) {
            int r0 = bd * BH;
            int ac = r0 - 1 > 0 ? r0 - 1 : 0;
            int bc = r0 + BH + 1 < 256 ? r0 + BH + 1 : 256;
            int rowsc = bc - ac;
            c1_band<<<dim3(64 * rowsc, GI), 256, 0, stream>>>(d_out, flag, wf + c1_wo, wf + c1_bo,
                                                              (bd & 1) ? hb1 : hb0,
                                                              g0, g0 + NB, r0, BH, ac, rowsc);
            if (bd > 0)
                final_band<<<dim3(BH, GI), 256, 0, stream>>>(((bd - 1) & 1) ? hb1 : hb0,
                                                             wf + c2_wo, wf + c2_bo, flag,
                                                             d_out, g0, (bd - 1) * BH, BH);
        }
        final_band<<<dim3(BH, GI), 256, 0, stream>>>(((nBands - 1) & 1) ? hb1 : hb0,
                                                     wf + c2_wo, wf + c2_bo, flag,
                                                     d_out, g0, (nBands - 1) * BH, BH);
    }
}

// Round 6
// 2420.479 us; speedup vs baseline: 1.6584x; 1.6584x over previous
//
#include <hip/hip_runtime.h>
#include <hip/hip_bf16.h>

typedef __hip_bfloat16 bf16;
typedef float f32x4 __attribute__((ext_vector_type(4)));

#define HW 65536
#define NB 8

__device__ __forceinline__ bf16 f2b(float v){ return __float2bfloat16(v); }
__device__ __forceinline__ float b2f(bf16 v){ return __bfloat162float(v); }

// wp[ct*84 + k] = w3[k*576 + ct], zero-pad k>=81 (ct = c*9 + tap)
__global__ void repack_w3(const float* __restrict__ w, float* __restrict__ wp)
{
    int p = blockIdx.x * 256 + threadIdx.x;
    if (p >= 576 * 84) return;
    int ct = p / 84, k = p - ct * 84;
    wp[p] = (k < 81) ? w[k * 576 + ct] : 0.f;
}

__global__ void d_kernel(const float* __restrict__ o, const float* __restrict__ r,
                         float* __restrict__ d)
{
    int i = blockIdx.x * 256 + threadIdx.x;
    d[i] = o[i] - r[i];
}

__global__ void s_kernel(const float* __restrict__ out0, const float* __restrict__ d,
                         float* __restrict__ s)
{
    int i = blockIdx.x * 256 + threadIdx.x;
    s[i] = out0[i] - d[i];
}

// One dyn-filter branch per block: 16x16 output tile.
// Fused conv1(1->16) -> conv2(16->64, produced 2ch at a time) -> conv3(64->81 into
// register logits) -> softmax -> 9x9 dynamic filter. Result packed bf16 into region1.
__global__ __launch_bounds__(256) void branch_kernel(
    const float* __restrict__ origin, const float* __restrict__ residual,
    const float* __restrict__ fxw1, const float* __restrict__ fxb1,
    const float* __restrict__ fxw2, const float* __restrict__ fxb2,
    const float* __restrict__ w3x,  const float* __restrict__ fxb3,
    const float* __restrict__ fgw1, const float* __restrict__ fgb1,
    const float* __restrict__ fgw2, const float* __restrict__ fgb2,
    const float* __restrict__ w3g,  const float* __restrict__ fgb3,
    bf16* __restrict__ pack)
{
    __shared__ float s_src[576];      // 24x24, origin core-4
    __shared__ float s_h1[6400];      // 16ch x 20x20, origin core-2
    __shared__ float s_h2[2][648];    // dbuf of channel-pairs, 2ch x 18x18, origin core-1

    const int t = threadIdx.x;
    const int tile = blockIdx.x;
    const int br = blockIdx.y >> 3;
    const int img = blockIdx.y & 7;
    const int y0 = (tile >> 4) << 4;
    const int x0 = (tile & 15) << 4;
    const long ib = (long)img * HW;

    const float* w1 = br ? fgw1 : fxw1;
    const float* b1 = br ? fgb1 : fxb1;
    const float* w2 = br ? fgw2 : fxw2;
    const float* b2 = br ? fgb2 : fxb2;
    const float* w3 = br ? w3g : w3x;
    const float* b3 = br ? fgb3 : fxb3;

    // ---- stage src (zero outside image; zero-pad matches conv 'same' and F.pad) ----
    for (int idx = t; idx < 576; idx += 256) {
        int sy = idx / 24, sx = idx - sy * 24;
        int gy = y0 - 4 + sy, gx = x0 - 4 + sx;
        float v = 0.f;
        if ((unsigned)gy < 256u && (unsigned)gx < 256u) {
            long o = ib + (gy << 8) + gx;
            v = br ? (origin[o] - residual[o]) : residual[o];
        }
        s_src[idx] = v;
    }
    __syncthreads();

    // ---- conv1 -> h1 (values at out-of-image coords forced to 0: conv2's zero pad) ----
    for (int o = t; o < 6400; o += 256) {
        int c = o / 400, p = o - c * 400;
        int hy = p / 20, hx = p - hy * 20;
        int gy = y0 - 2 + hy, gx = x0 - 2 + hx;
        float a = b1[c];
        const float* wc = w1 + c * 9;
        #pragma unroll
        for (int dy = 0; dy < 3; dy++)
            #pragma unroll
            for (int dx = 0; dx < 3; dx++)
                a = fmaf(wc[dy * 3 + dx], s_src[(hy + 1 + dy) * 24 + hx + 1 + dx], a);
        a = fmaxf(a, 0.f);
        s_h1[o] = ((unsigned)gy < 256u && (unsigned)gx < 256u) ? a : 0.f;
    }
    __syncthreads();

    const int ly = t >> 4, lx = t & 15;

    // ---- logits in registers: 84 = 21 x f32x4, pads = -1e30 (exp -> 0) ----
    f32x4 L[21];
    #pragma unroll
    for (int q = 0; q < 21; q++) {
        #pragma unroll
        for (int r = 0; r < 4; r++) {
            int k = 4 * q + r;
            L[q][r] = (k < 81) ? b3[k] : -1e30f;
        }
    }

    for (int c = 0; c < 64; c += 2) {
        const int pb = (c >> 1) & 1;
        // produce h2 channels c, c+1 (shared h1 reads)
        #pragma unroll
        for (int rnd = 0; rnd < 2; rnd++) {
            int p = t + rnd * 256;
            if (p < 324) {
                int hy = p / 18, hx = p - hy * 18;
                int gy = y0 - 1 + hy, gx = x0 - 1 + hx;
                float a0 = b2[c], a1 = b2[c + 1];
                const float* wa = w2 + c * 144;
                const float* wb = wa + 144;
                for (int c1 = 0; c1 < 16; c1++) {
                    const float* h1r = s_h1 + c1 * 400 + hy * 20 + hx;
                    #pragma unroll
                    for (int dy = 0; dy < 3; dy++)
                        #pragma unroll
                        for (int dx = 0; dx < 3; dx++) {
                            float v = h1r[dy * 20 + dx];
                            a0 = fmaf(wa[c1 * 9 + dy * 3 + dx], v, a0);
                            a1 = fmaf(wb[c1 * 9 + dy * 3 + dx], v, a1);
                        }
                }
                bool in = (unsigned)gy < 256u && (unsigned)gx < 256u;
                s_h2[pb][p]       = in ? fmaxf(a0, 0.f) : 0.f;
                s_h2[pb][324 + p] = in ? fmaxf(a1, 0.f) : 0.f;
            }
        }
        __syncthreads();
        // consume: accumulate both channels into logits (w3 rows wave-uniform -> s_loads)
        for (int cc = 0; cc < 2; cc++) {
            const float* w3c = w3 + (c + cc) * 9 * 84;
            const float* hb = s_h2[pb] + cc * 324;
            #pragma unroll
            for (int t9 = 0; t9 < 9; t9++) {
                float v = hb[(ly + t9 / 3) * 18 + lx + (t9 % 3)];
                const float* wr = w3c + t9 * 84;
                #pragma unroll
                for (int q = 0; q < 21; q++) {
                    f32x4 wv = *(const f32x4*)(wr + 4 * q);
                    L[q][0] = fmaf(v, wv[0], L[q][0]);
                    L[q][1] = fmaf(v, wv[1], L[q][1]);
                    L[q][2] = fmaf(v, wv[2], L[q][2]);
                    L[q][3] = fmaf(v, wv[3], L[q][3]);
                }
            }
        }
        // no extra barrier needed: next produce targets the other buffer, and the
        // sync above guarantees everyone finished consuming it two pairs ago.
    }

    // ---- softmax over taps (pads give exp(-huge)=0) ----
    float m = L[0][0];
    #pragma unroll
    for (int q = 0; q < 21; q++)
        m = fmaxf(m, fmaxf(fmaxf(L[q][0], L[q][1]), fmaxf(L[q][2], L[q][3])));
    float ssum = 0.f;
    #pragma unroll
    for (int q = 0; q < 21; q++) {
        #pragma unroll
        for (int r = 0; r < 4; r++) {
            float e = __expf(L[q][r] - m);
            L[q][r] = e;
            ssum += e;
        }
    }
    float inv = 1.f / ssum;

    // ---- 9x9 dynamic filter on src ----
    float acc = 0.f;
    #pragma unroll
    for (int i = 0; i < 9; i++)
        #pragma unroll
        for (int j = 0; j < 9; j++) {
            int k = i * 9 + j;
            acc = fmaf(L[k >> 2][k & 3], s_src[(ly + i) * 24 + lx + j], acc);
        }

    pack[((img * 2 + br) << 16) + ((y0 + ly) << 8) + (x0 + lx)] = f2b(acc * inv);
}

// c1(2->64)+c2(64->1) fused per tile; out0 = s + d
__global__ __launch_bounds__(256) void tail_kernel(
    const bf16* __restrict__ pack,
    const float* __restrict__ c1w, const float* __restrict__ c1b,
    const float* __restrict__ c2w, const float* __restrict__ c2b,
    const float* __restrict__ d2, float* __restrict__ out0)
{
    __shared__ float s_x[400], s_g[400];   // 20x20, origin core-2
    __shared__ float s_h[2][324];          // dbuf h channel, 18x18, origin core-1

    const int t = threadIdx.x;
    const int tile = blockIdx.x;
    const int img = blockIdx.y;
    const int y0 = (tile >> 4) << 4, x0 = (tile & 15) << 4;

    for (int idx = t; idx < 400; idx += 256) {
        int hy = idx / 20, hx = idx - hy * 20;
        int gy = y0 - 2 + hy, gx = x0 - 2 + hx;
        float vx = 0.f, vg = 0.f;
        if ((unsigned)gy < 256u && (unsigned)gx < 256u) {
            int o = (gy << 8) + gx;
            vx = b2f(pack[((img * 2 + 0) << 16) + o]);
            vg = b2f(pack[((img * 2 + 1) << 16) + o]);
        }
        s_x[idx] = vx;
        s_g[idx] = vg;
    }
    __syncthreads();

    const int ly = t >> 4, lx = t & 15;
    float sacc = c2b[0];

    for (int c = 0; c < 64; c++) {
        const int pb = c & 1;
        #pragma unroll
        for (int rnd = 0; rnd < 2; rnd++) {
            int p = t + rnd * 256;
            if (p < 324) {
                int hy = p / 18, hx = p - hy * 18;
                int gy = y0 - 1 + hy, gx = x0 - 1 + hx;
                float a = c1b[c];
                const float* wx = c1w + c * 18;
                #pragma unroll
                for (int dy = 0; dy < 3; dy++)
                    #pragma unroll
                    for (int dx = 0; dx < 3; dx++) {
                        a = fmaf(wx[dy * 3 + dx],     s_x[(hy + dy) * 20 + hx + dx], a);
                        a = fmaf(wx[9 + dy * 3 + dx], s_g[(hy + dy) * 20 + hx + dx], a);
                    }
                bool in = (unsigned)gy < 256u && (unsigned)gx < 256u;
                s_h[pb][p] = in ? fmaxf(a, 0.f) : 0.f;
            }
        }
        __syncthreads();
        const float* wc = c2w + c * 9;
        #pragma unroll
        for (int t9 = 0; t9 < 9; t9++)
            sacc = fmaf(wc[t9], s_h[pb][(ly + t9 / 3) * 18 + lx + (t9 % 3)], sacc);
    }
    long o = (long)img * HW + ((y0 + ly) << 8) + (x0 + lx);
    out0[o] = sacc + d2[o];
}

extern "C" void kernel_launch(void* const* d_in, const int* in_sizes, int n_in,
                              void* d_out, int out_size, void* d_ws, size_t ws_size,
                              hipStream_t stream)
{
    const float* origin   = (const float*)d_in[0];
    const float* residual = (const float*)d_in[1];
    const float* fxw1 = (const float*)d_in[2];  const float* fxb1 = (const float*)d_in[3];
    const float* fxw2 = (const float*)d_in[4];  const float* fxb2 = (const float*)d_in[5];
    const float* fxw3 = (const float*)d_in[6];  const float* fxb3 = (const float*)d_in[7];
    const float* fgw1 = (const float*)d_in[8];  const float* fgb1 = (const float*)d_in[9];
    const float* fgw2 = (const float*)d_in[10]; const float* fgb2 = (const float*)d_in[11];
    const float* fgw3 = (const float*)d_in[12]; const float* fgb3 = (const float*)d_in[13];
    const float* c1w  = (const float*)d_in[14]; const float* c1b  = (const float*)d_in[15];
    const float* c2w  = (const float*)d_in[16]; const float* c2b  = (const float*)d_in[17];

    float* out0 = (float*)d_out;                 // out = s + d
    float* out1 = out0 + (long)NB * HW;          // s   (temp: packed bf16 x_/g_)
    float* out2 = out1 + (long)NB * HW;          // d
    bf16*  pack = (bf16*)out1;                   // 2*8*65536*2B = 2MB = region1 exactly

    float* ws  = (float*)d_ws;
    float* w3x = ws;                             // 576*84 f32
    float* w3g = ws + 576 * 84;

    repack_w3<<<(576 * 84 + 255) / 256, 256, 0, stream>>>(fxw3, w3x);
    repack_w3<<<(576 * 84 + 255) / 256, 256, 0, stream>>>(fgw3, w3g);
    d_kernel<<<(NB * HW) / 256, 256, 0, stream>>>(origin, residual, out2);

    branch_kernel<<<dim3(256, 16), 256, 0, stream>>>(
        origin, residual,
        fxw1, fxb1, fxw2, fxb2, w3x, fxb3,
        fgw1, fgb1, fgw2, fgb2, w3g, fgb3, pack);

    tail_kernel<<<dim3(256, 8), 256, 0, stream>>>(pack, c1w, c1b, c2w, c2b, out2, out0);

    s_kernel<<<(NB * HW) / 256, 256, 0, stream>>>(out0, out2, out1);
}

// Round 7
// 571.730 us; speedup vs baseline: 7.0209x; 4.2336x over previous
//
#include <hip/hip_runtime.h>
#include <hip/hip_bf16.h>

typedef __hip_bfloat16 bf16;
typedef float f32x4 __attribute__((ext_vector_type(4)));
typedef short bf16x8 __attribute__((ext_vector_type(8)));

#define HW 65536
#define NB 8

__device__ __forceinline__ bf16 f2b(float v){ return __float2bfloat16(v); }
__device__ __forceinline__ float b2f(bf16 v){ return __bfloat162float(v); }
__device__ __forceinline__ short fbits(float v){ bf16 b = f2b(v); return *(short*)&b; }

// ---- B-operand packing: lane-ordered 16B lines so B-frag = one 16B load ----
// conv3: k = tap*64 + c (K=576), n in [0,96), zero n>=81.  per-branch 18*6*64*8
__global__ void pack_w3(const float* __restrict__ wx, const float* __restrict__ wg,
                        short* __restrict__ dst)
{
    int idx = blockIdx.x * 256 + threadIdx.x;
    if (idx >= 110592) return;
    int br = idx / 55296, r = idx % 55296;
    int ks = r / 3072, r2 = r % 3072;
    int nc = r2 >> 9, r3 = r2 & 511;
    int lane = r3 >> 3, j = r3 & 7;
    int n = nc * 16 + (lane & 15);
    int k = ks * 32 + ((lane >> 4) << 3) + j;
    int tap = k >> 6, c = k & 63;
    const float* w = br ? wg : wx;
    dst[idx] = fbits((n < 81) ? w[n * 576 + c * 9 + tap] : 0.f);
}

// conv2: k = tap*16 + c (K=160, taps 9 zero), n in [0,64). per-branch 5*4*64*8
__global__ void pack_w2(const float* __restrict__ wx, const float* __restrict__ wg,
                        short* __restrict__ dst)
{
    int idx = blockIdx.x * 256 + threadIdx.x;
    if (idx >= 20480) return;
    int br = idx / 10240, r = idx % 10240;
    int ks = r / 2048, r2 = r % 2048;
    int nc = r2 >> 9, r3 = r2 & 511;
    int lane = r3 >> 3, j = r3 & 7;
    int n = nc * 16 + (lane & 15);
    int k = ks * 32 + ((lane >> 4) << 3) + j;
    int tap = k >> 4, c = k & 15;
    const float* w = br ? wg : wx;
    dst[idx] = fbits((tap < 9) ? w[n * 144 + c * 9 + tap] : 0.f);
}

__global__ void d_kernel(const float* __restrict__ o, const float* __restrict__ r,
                         float* __restrict__ d)
{
    int i = blockIdx.x * 256 + threadIdx.x;
    d[i] = o[i] - r[i];
}

__global__ void s_kernel(const float* __restrict__ out0, const float* __restrict__ d,
                         float* __restrict__ s)
{
    int i = blockIdx.x * 256 + threadIdx.x;
    s[i] = out0[i] - d[i];
}

// One dyn-filter branch per block: 16x16 output tile.
// conv1 (VALU) -> h1 bf16 ch-last -> conv2 (MFMA) -> h2 bf16 ch-last swizzled
// -> conv3 (MFMA, 96 logits in acc) -> register softmax + 9x9 filter.
__global__ __launch_bounds__(256) void branch_kernel(
    const float* __restrict__ origin, const float* __restrict__ residual,
    const float* __restrict__ fxw1, const float* __restrict__ fxb1,
    const float* __restrict__ fxb2, const float* __restrict__ fxb3,
    const float* __restrict__ fgw1, const float* __restrict__ fgb1,
    const float* __restrict__ fgb2, const float* __restrict__ fgb3,
    const short* __restrict__ Bp2, const short* __restrict__ Bp3,
    bf16* __restrict__ pack)
{
    __shared__ float s_src[576];     // 24x24 f32
    __shared__ bf16  s_h1[6720];     // [21][20][16] ch-last, row20 = 0 (K-pad)
    __shared__ bf16  s_h2[20736];    // [324][64] ch-last, XOR-swizzled

    const int t = threadIdx.x;
    const int lane = t & 63;
    const int w = t >> 6;            // wave 0..3
    const int g = lane >> 4;         // k-group / D-row-group
    const int j16 = lane & 15;
    const int tile = blockIdx.x;
    const int br = blockIdx.y >> 3;
    const int img = blockIdx.y & 7;
    const int y0 = (tile >> 4) << 4, x0 = (tile & 15) << 4;
    const long ib = (long)img * HW;

    const float* w1 = br ? fgw1 : fxw1;
    const float* b1 = br ? fgb1 : fxb1;
    const float* b2 = br ? fgb2 : fxb2;
    const float* b3 = br ? fgb3 : fxb3;
    const short* Bw2 = Bp2 + br * 10240;
    const short* Bw3 = Bp3 + br * 55296;

    // ---- phase 1: stage src (24x24, zero outside image) ----
    for (int idx = t; idx < 576; idx += 256) {
        int sy = idx / 24, sx = idx - sy * 24;
        int gy = y0 - 4 + sy, gx = x0 - 4 + sx;
        float v = 0.f;
        if ((unsigned)gy < 256u && (unsigned)gx < 256u) {
            long o = ib + (gy << 8) + gx;
            v = br ? (origin[o] - residual[o]) : residual[o];
        }
        s_src[idx] = v;
    }
    __syncthreads();

    // ---- phase 2: conv1 (1->16) f32 VALU -> h1 bf16 ch-last; zero K-pad row ----
    for (int p = t; p < 400; p += 256) {
        int py = p / 20, px = p - py * 20;
        int gy = y0 - 2 + py, gx = x0 - 2 + px;
        bool in = (unsigned)gy < 256u && (unsigned)gx < 256u;
        float sw[9];
        #pragma unroll
        for (int dy = 0; dy < 3; dy++)
            #pragma unroll
            for (int dx = 0; dx < 3; dx++)
                sw[dy * 3 + dx] = s_src[(py + 1 + dy) * 24 + px + 1 + dx];
        #pragma unroll
        for (int c = 0; c < 16; c++) {
            float a = b1[c];
            const float* wc = w1 + c * 9;
            #pragma unroll
            for (int q = 0; q < 9; q++) a = fmaf(wc[q], sw[q], a);
            a = fmaxf(a, 0.f);
            s_h1[p * 16 + c] = f2b(in ? a : 0.f);
        }
    }
    for (int idx = t; idx < 320; idx += 256) s_h1[6400 + idx] = f2b(0.f);
    __syncthreads();

    // ---- phase 3: conv2 (16->64) MFMA. M=336(21 rows of 16), N=64, K=160 ----
    {
        bf16x8 B2[5][4];
        #pragma unroll
        for (int ks = 0; ks < 5; ks++)
            #pragma unroll
            for (int nc = 0; nc < 4; nc++)
                B2[ks][nc] = *(const bf16x8*)(Bw2 + ((ks * 4 + nc) * 64 + lane) * 8);
        const int kgh = g >> 1, c0 = (g & 1) * 8;
        for (int mrow = w; mrow < 21; mrow += 4) {
            int pA = mrow * 16 + j16;
            int pyA = pA / 18, pxA = pA - pyA * 18;
            f32x4 acc2[4];
            #pragma unroll
            for (int nc = 0; nc < 4; nc++) {
                float bb = b2[nc * 16 + j16];
                acc2[nc] = (f32x4){bb, bb, bb, bb};
            }
            for (int ks = 0; ks < 5; ks++) {
                int tap = 2 * ks + kgh;
                int ty = (tap * 11) >> 5;          // tap/3 for tap<=9
                int tx = tap - ty * 3;
                int pl = (pyA + ty) * 20 + pxA + tx;
                if (pl > 419) pl = 419;            // clamp (garbage rows discarded)
                bf16x8 A = *(const bf16x8*)&s_h1[pl * 16 + c0];
                #pragma unroll
                for (int nc = 0; nc < 4; nc++)
                    acc2[nc] = __builtin_amdgcn_mfma_f32_16x16x32_bf16(A, B2[ks][nc], acc2[nc], 0, 0, 0);
            }
            #pragma unroll
            for (int nc = 0; nc < 4; nc++) {
                int ch = nc * 16 + j16;
                #pragma unroll
                for (int r = 0; r < 4; r++) {
                    int p = mrow * 16 + g * 4 + r;
                    if (p < 324) {
                        int off = (p * 128 + ch * 2) ^ ((p & 7) << 4);
                        *(bf16*)((char*)s_h2 + off) = f2b(fmaxf(acc2[nc][r], 0.f));
                    }
                }
            }
        }
    }
    __syncthreads();

    // ---- phase 4: conv3 (64->81) MFMA. M=256 (wave: 4 rows), N=96, K=576 ----
    int ti[6], tj[6];
    #pragma unroll
    for (int nc = 0; nc < 6; nc++) {
        int n = nc * 16 + j16;
        int tt = n / 9;
        ti[nc] = tt; tj[nc] = n - tt * 9;
    }
    f32x4 acc[4][6];
    #pragma unroll
    for (int mr = 0; mr < 4; mr++)
        #pragma unroll
        for (int nc = 0; nc < 6; nc++) {
            int n = nc * 16 + j16;
            float bb = (n < 81) ? b3[n] : -1e30f;
            acc[mr][nc] = (f32x4){bb, bb, bb, bb};
        }
    for (int ks = 0; ks < 18; ks++) {
        bf16x8 B3[6];
        #pragma unroll
        for (int nc = 0; nc < 6; nc++)
            B3[nc] = *(const bf16x8*)(Bw3 + ((ks * 6 + nc) * 64 + lane) * 8);
        int tap = ks >> 1;
        int dy = (tap * 11) >> 5;
        int dx = tap - dy * 3;
        int c0 = ((ks & 1) << 5) + (g << 3);
        #pragma unroll
        for (int mr = 0; mr < 4; mr++) {
            int mrow = w * 4 + mr;
            int pl = (mrow + dy) * 18 + j16 + dx;
            int off = (pl * 128 + c0 * 2) ^ ((pl & 7) << 4);
            bf16x8 A = *(const bf16x8*)((const char*)s_h2 + off);
            #pragma unroll
            for (int nc = 0; nc < 6; nc++)
                acc[mr][nc] = __builtin_amdgcn_mfma_f32_16x16x32_bf16(A, B3[nc], acc[mr][nc], 0, 0, 0);
        }
    }

    // ---- phase 5: register softmax (over 16 lanes x 6 ncols) + 9x9 filter ----
    #pragma unroll
    for (int mr = 0; mr < 4; mr++) {
        int mrow = w * 4 + mr;
        bf16 res[4];
        #pragma unroll
        for (int r = 0; r < 4; r++) {
            float mx = -1e30f;
            #pragma unroll
            for (int nc = 0; nc < 6; nc++) mx = fmaxf(mx, acc[mr][nc][r]);
            #pragma unroll
            for (int msk = 1; msk < 16; msk <<= 1) mx = fmaxf(mx, __shfl_xor(mx, msk));
            float ssum = 0.f, fsum = 0.f;
            int px = g * 4 + r;
            #pragma unroll
            for (int nc = 0; nc < 6; nc++) {
                float e = __expf(acc[mr][nc][r] - mx);   // pads: exp(-1e30-..) = 0
                ssum += e;
                int idx = (mrow + ti[nc]) * 24 + px + tj[nc];
                fsum += e * s_src[idx > 575 ? 575 : idx];
            }
            #pragma unroll
            for (int msk = 1; msk < 16; msk <<= 1) {
                ssum += __shfl_xor(ssum, msk);
                fsum += __shfl_xor(fsum, msk);
            }
            res[r] = f2b(fsum / ssum);
        }
        if (j16 == 0) {
            long base = ((long)(img * 2 + br) << 16) + ((y0 + mrow) << 8) + x0 + g * 4;
            pack[base + 0] = res[0];
            pack[base + 1] = res[1];
            pack[base + 2] = res[2];
            pack[base + 3] = res[3];
        }
    }
}

// c1(2->64)+c2(64->1) fused per tile; out0 = s + d  (unchanged from R6)
__global__ __launch_bounds__(256) void tail_kernel(
    const bf16* __restrict__ pack,
    const float* __restrict__ c1w, const float* __restrict__ c1b,
    const float* __restrict__ c2w, const float* __restrict__ c2b,
    const float* __restrict__ d2, float* __restrict__ out0)
{
    __shared__ float s_x[400], s_g[400];
    __shared__ float s_h[2][324];

    const int t = threadIdx.x;
    const int tile = blockIdx.x;
    const int img = blockIdx.y;
    const int y0 = (tile >> 4) << 4, x0 = (tile & 15) << 4;

    for (int idx = t; idx < 400; idx += 256) {
        int hy = idx / 20, hx = idx - hy * 20;
        int gy = y0 - 2 + hy, gx = x0 - 2 + hx;
        float vx = 0.f, vg = 0.f;
        if ((unsigned)gy < 256u && (unsigned)gx < 256u) {
            int o = (gy << 8) + gx;
            vx = b2f(pack[((img * 2 + 0) << 16) + o]);
            vg = b2f(pack[((img * 2 + 1) << 16) + o]);
        }
        s_x[idx] = vx;
        s_g[idx] = vg;
    }
    __syncthreads();

    const int ly = t >> 4, lx = t & 15;
    float sacc = c2b[0];

    for (int c = 0; c < 64; c++) {
        const int pb = c & 1;
        #pragma unroll
        for (int rnd = 0; rnd < 2; rnd++) {
            int p = t + rnd * 256;
            if (p < 324) {
                int hy = p / 18, hx = p - hy * 18;
                int gy = y0 - 1 + hy, gx = x0 - 1 + hx;
                float a = c1b[c];
                const float* wx = c1w + c * 18;
                #pragma unroll
                for (int dy = 0; dy < 3; dy++)
                    #pragma unroll
                    for (int dx = 0; dx < 3; dx++) {
                        a = fmaf(wx[dy * 3 + dx],     s_x[(hy + dy) * 20 + hx + dx], a);
                        a = fmaf(wx[9 + dy * 3 + dx], s_g[(hy + dy) * 20 + hx + dx], a);
                    }
                bool in = (unsigned)gy < 256u && (unsigned)gx < 256u;
                s_h[pb][p] = in ? fmaxf(a, 0.f) : 0.f;
            }
        }
        __syncthreads();
        const float* wc = c2w + c * 9;
        #pragma unroll
        for (int t9 = 0; t9 < 9; t9++)
            sacc = fmaf(wc[t9], s_h[pb][(ly + t9 / 3) * 18 + lx + (t9 % 3)], sacc);
    }
    long o = (long)img * HW + ((y0 + ly) << 8) + (x0 + lx);
    out0[o] = sacc + d2[o];
}

extern "C" void kernel_launch(void* const* d_in, const int* in_sizes, int n_in,
                              void* d_out, int out_size, void* d_ws, size_t ws_size,
                              hipStream_t stream)
{
    const float* origin   = (const float*)d_in[0];
    const float* residual = (const float*)d_in[1];
    const float* fxw1 = (const float*)d_in[2];  const float* fxb1 = (const float*)d_in[3];
    const float* fxw2 = (const float*)d_in[4];  const float* fxb2 = (const float*)d_in[5];
    const float* fxw3 = (const float*)d_in[6];  const float* fxb3 = (const float*)d_in[7];
    const float* fgw1 = (const float*)d_in[8];  const float* fgb1 = (const float*)d_in[9];
    const float* fgw2 = (const float*)d_in[10]; const float* fgb2 = (const float*)d_in[11];
    const float* fgw3 = (const float*)d_in[12]; const float* fgb3 = (const float*)d_in[13];
    const float* c1w  = (const float*)d_in[14]; const float* c1b  = (const float*)d_in[15];
    const float* c2w  = (const float*)d_in[16]; const float* c2b  = (const float*)d_in[17];

    float* out0 = (float*)d_out;                 // out = s + d
    float* out1 = out0 + (long)NB * HW;          // s   (temp: packed bf16 x_/g_)
    float* out2 = out1 + (long)NB * HW;          // d
    bf16*  pack = (bf16*)out1;

    short* Bp2 = (short*)d_ws;                   // 20480 shorts
    short* Bp3 = Bp2 + 20480;                    // 110592 shorts (total 262KB)

    pack_w2<<<(20480 + 255) / 256, 256, 0, stream>>>(fxw2, fgw2, Bp2);
    pack_w3<<<(110592 + 255) / 256, 256, 0, stream>>>(fxw3, fgw3, Bp3);
    d_kernel<<<(NB * HW) / 256, 256, 0, stream>>>(origin, residual, out2);

    branch_kernel<<<dim3(256, 16), 256, 0, stream>>>(
        origin, residual,
        fxw1, fxb1, fxb2, fxb3,
        fgw1, fgb1, fgb2, fgb3,
        Bp2, Bp3, pack);

    tail_kernel<<<dim3(256, 8), 256, 0, stream>>>(pack, c1w, c1b, c2w, c2b, out2, out0);

    s_kernel<<<(NB * HW) / 256, 256, 0, stream>>>(out0, out2, out1);
}